// Round 7
// baseline (72.894 us; speedup 1.0000x reference)
//
#include <hip/hip_runtime.h>

// MesoLayer R6: reg-staged (T14) double-buffered pipeline, 4 blocks/CU.
// Block = 256 threads = 128 rows; 16 chunks x 8 rows (780 float4 each,
// contiguous in global). Phase p:
//   flush(p-1) -> compute(p) from LDS buf[p&1] -> ds_write regs(chunk p+1)
//   -> issue plain global loads(chunk p+2) into regs -> lgkm0 + s_barrier.
// No vmcnt drains anywhere: loads stay in flight across barriers; the
// compiler inserts the exact vmcnt before the ds_write that consumes regs.
// Compute: 64 lanes per segment: lane=(q=t&7, r=(t>>3)&7) covers row r,
// j in {q, q+8, ...}; reduce over q via shfl_xor 1/2/4 (DPP-cheap); true
// global max -> single-pass exp (no online rescale).

static __device__ __forceinline__ float xsum(float a) {
  a += __shfl_xor(a, 1, 64);
  a += __shfl_xor(a, 2, 64);
  a += __shfl_xor(a, 4, 64);
  return a;
}
static __device__ __forceinline__ float xmax(float a) {
  a = fmaxf(a, __shfl_xor(a, 1, 64));
  a = fmaxf(a, __shfl_xor(a, 2, 64));
  a = fmaxf(a, __shfl_xor(a, 4, 64));
  return a;
}

// Mt = upper-tri of M = W W^T, 15 entries; T maps (g,h) -> tri index.
template<int L, int SEGOFF, int OUTOFF>
__device__ __forceinline__ void seg64(const float* __restrict__ bp, int q,
                                      const float (&Mt)[15],
                                      float* __restrict__ ob) {
  constexpr int T[5][5] = {{0, 1, 2, 3, 4},  {1, 5, 6, 7, 8},
                           {2, 6, 9, 10, 11}, {3, 7, 10, 12, 13},
                           {4, 8, 11, 13, 14}};
  constexpr int NJ = (L + 7) / 8;
  const bool lastv = (q + 8 * (NJ - 1)) < L;

  float s[NJ][5];
#pragma unroll
  for (int k = 0; k < NJ; ++k) {
    int j = q + 8 * k;
    if (j > L - 1) j = L - 1;  // only last k can clamp
#pragma unroll
    for (int g = 0; g < 5; ++g) s[k][g] = bp[SEGOFF + j * 5 + g];
  }
#pragma unroll
  for (int g = 0; g < 5; ++g) s[NJ - 1][g] = lastv ? s[NJ - 1][g] : 0.f;

  float ssl[5];
#pragma unroll
  for (int g = 0; g < 5; ++g) {
    float a = s[0][g];
#pragma unroll
    for (int k = 1; k < NJ; ++k) a += s[k][g];
    ssl[g] = xsum(a);  // full subsum, all lanes
  }

  float v[5];
#pragma unroll
  for (int g = 0; g < 5; ++g) {
    float a = Mt[T[g][0]] * ssl[0];
#pragma unroll
    for (int h = 1; h < 5; ++h) a += Mt[T[g][h]] * ssl[h];
    v[g] = a;
  }

  float sc[NJ];
#pragma unroll
  for (int k = 0; k < NJ; ++k) {
    float a = s[k][0] * v[0];
#pragma unroll
    for (int g = 1; g < 5; ++g) a += s[k][g] * v[g];
    sc[k] = a;
  }
  sc[NJ - 1] = lastv ? sc[NJ - 1] : -3.0e38f;

  float ml = sc[0];
#pragma unroll
  for (int k = 1; k < NJ; ++k) ml = fmaxf(ml, sc[k]);
  float m = xmax(ml);  // true global max -> single-pass exp below

  float d = 0.f, pl[5] = {0.f, 0.f, 0.f, 0.f, 0.f};
#pragma unroll
  for (int k = 0; k < NJ; ++k) {
    float e = __expf(sc[k] - m);  // masked k: exp(-huge)=0
    d += e;
#pragma unroll
    for (int g = 0; g < 5; ++g) pl[g] += e * s[k][g];
  }
  d = xsum(d);
  float inv = 1.0f / d;
#pragma unroll
  for (int g = 0; g < 5; ++g) pl[g] = xsum(pl[g]);
  if (q == 0) {
#pragma unroll
    for (int g = 0; g < 5; ++g) ob[OUTOFF + g] = pl[g] * inv;
  }
}

// LDS (floats): buf0 [0,3120) | buf1 [3120,6240) | out0 [6240,6520) |
// out1 [6520,6800). Total 27200 B -> 4+ blocks/CU.
__global__ __launch_bounds__(256, 4) void meso_kernel(
    const float* __restrict__ x, const float* __restrict__ w,
    float* __restrict__ out) {
  __shared__ __align__(16) float smf[6800];
  float4* sm4 = (float4*)smf;
  const int t = threadIdx.x;
  const int wv = t >> 6, q = t & 7, r = (t >> 3) & 7;
  const float4* xp4 = (const float4*)x + (size_t)blockIdx.x * 12480;  // 128*390/4
  float4* o4 = (float4*)out + (size_t)blockIdx.x * 1120;              // 128*35/4

  float4 A0, A1, A2, A3, B0, B1, B2, B3;

#define ISSUE(R0_, R1_, R2_, R3_, c)                        \
  { const float4* gp_ = xp4 + (c) * 780;                    \
    R0_ = gp_[t]; R1_ = gp_[t + 256]; R2_ = gp_[t + 512];   \
    if (t < 12) R3_ = gp_[t + 768]; }

#define WRITE(R0_, R1_, R2_, R3_, b)                        \
  { float4* lp_ = sm4 + (b) * 780;                          \
    lp_[t] = R0_; lp_[t + 256] = R1_; lp_[t + 512] = R2_;   \
    if (t < 12) lp_[t + 768] = R3_; }

#define COMPUTE(par)                                                     \
  { const float* bp = smf + (par) * 3120 + r * 390;                      \
    float* ob = smf + 6240 + (par) * 280 + r * 35;                       \
    if (wv == 0) { seg64<25, 115, 15>(bp, q, Mt, ob); }                  \
    else if (wv == 1) { seg64<12, 330, 30>(bp, q, Mt, ob);               \
                        seg64<5, 0, 0>(bp, q, Mt, ob); }                 \
    else if (wv == 2) { seg64<9, 25, 5>(bp, q, Mt, ob);                  \
                        seg64<9, 70, 10>(bp, q, Mt, ob); }               \
    else { seg64<9, 240, 20>(bp, q, Mt, ob);                             \
           seg64<9, 285, 25>(bp, q, Mt, ob); } }

#define FLUSH(pp)                                                        \
  { if (t < 70) o4[(pp) * 70 + t] = sm4[1560 + ((pp) & 1) * 70 + t]; }

#define BAR()                                               \
  { asm volatile("s_waitcnt lgkmcnt(0)" ::: "memory");      \
    __builtin_amdgcn_s_barrier(); }

  ISSUE(A0, A1, A2, A3, 0)

  // Mt = upper-tri of W W^T (w uniform -> scalar loads, resolved pre-loop)
  float Mt[15];
  {
    int i = 0;
#pragma unroll
    for (int g = 0; g < 5; ++g)
#pragma unroll
      for (int h = g; h < 5; ++h, ++i) {
        float a = 0.f;
#pragma unroll
        for (int k = 0; k < 10; ++k) a += w[g * 10 + k] * w[h * 10 + k];
        Mt[i] = a;
      }
  }

  WRITE(A0, A1, A2, A3, 0)  // one-time stall on chunk-0 loads
  ISSUE(B0, B1, B2, B3, 1)
  BAR()

#pragma unroll 1
  for (int p = 0; p < 16; p += 2) {
    // even phase p: buf0/out0; regs B hold chunk p+1
    if (p > 0) FLUSH(p - 1)
    COMPUTE(0)
    WRITE(B0, B1, B2, B3, 1)                 // exact vmcnt wait on B only
    if (p + 2 <= 15) ISSUE(A0, A1, A2, A3, p + 2)
    BAR()

    // odd phase p+1: buf1/out1; regs A hold chunk p+2
    FLUSH(p)
    COMPUTE(1)
    if (p + 2 <= 15) WRITE(A0, A1, A2, A3, 0)
    if (p + 3 <= 15) ISSUE(B0, B1, B2, B3, p + 3)
    BAR()
  }
  FLUSH(15)
}

extern "C" void kernel_launch(void* const* d_in, const int* in_sizes, int n_in,
                              void* d_out, int out_size, void* d_ws, size_t ws_size,
                              hipStream_t stream) {
  const float* x = (const float*)d_in[0];
  const float* w = (const float*)d_in[1];
  float* out = (float*)d_out;
  int B = in_sizes[0] / 390;  // 131072
  int grid = B / 128;         // 1024 blocks = 4/CU
  meso_kernel<<<grid, 256, 0, stream>>>(x, w, out);
}